// Round 1
// 345.021 us; speedup vs baseline: 1.0539x; 1.0539x over previous
//
#include <hip/hip_runtime.h>
#include <hip/hip_bf16.h>

#define BATCH 4096

typedef __attribute__((ext_vector_type(8))) short short8;
typedef __attribute__((ext_vector_type(4))) short short4_t;
typedef __attribute__((ext_vector_type(4))) float f32x4;

#define MFMA_BF16 __builtin_amdgcn_mfma_f32_16x16x32_bf16

__device__ __forceinline__ float frelu(float v) { return v > 0.f ? v : 0.f; }
__device__ __forceinline__ unsigned short f2bf(float f) {
    return __builtin_bit_cast(unsigned short, __float2bfloat16(f));
}
__device__ __forceinline__ short8 cvt8(const float* p) {
    float4 a = *(const float4*)p;
    float4 b = *(const float4*)(p + 4);
    short8 r;
    r[0] = (short)f2bf(a.x); r[1] = (short)f2bf(a.y); r[2] = (short)f2bf(a.z); r[3] = (short)f2bf(a.w);
    r[4] = (short)f2bf(b.x); r[5] = (short)f2bf(b.y); r[6] = (short)f2bf(b.z); r[7] = (short)f2bf(b.w);
    return r;
}

// ---------------- prep: permute+cvt weights to bf16 K-contiguous layouts; init out ----------------
// w2p[oc][khw*32+ic], w3p[oc][khw*64+ic], w4p[n][pos*64+oc]; out[0..8191]=b5; ave tail zero.
__global__ __launch_bounds__(256) void prep_kernel(const float* __restrict__ w2, const float* __restrict__ w3,
                                                   const float* __restrict__ w4, const float* __restrict__ b5,
                                                   unsigned short* __restrict__ w2p, unsigned short* __restrict__ w3p,
                                                   unsigned short* __restrict__ w4p, float* __restrict__ out) {
    int idx = blockIdx.x * 256 + threadIdx.x;
    if (idx < 18432) {
        int oc = idx / 288, k = idx % 288;
        int khw = k / 32, ic = k % 32;
        w2p[idx] = f2bf(w2[oc * 288 + ic * 9 + khw]);
    } else if (idx < 55296) {
        int j = idx - 18432;
        int oc = j / 576, k = j % 576;
        int khw = k / 64, ic = k % 64;
        w3p[j] = f2bf(w3[oc * 576 + ic * 9 + khw]);
    } else if (idx < 546816) {
        int j = idx - 55296;
        int n = j / 960, k = j % 960;
        int pos = k / 64, oc = k % 64;
        w4p[j] = f2bf(w4[n * 960 + oc * 15 + pos]);
    } else if (idx < 555008) {
        int j = idx - 546816;
        out[j] = b5[j & 1];
    } else if (idx < 555223) {
        out[8192 + (idx - 555008)] = 0.f;
    }
}

// ---------------- conv1 (MFMA, LDS-staged): x[B,3,48,64]*w1[32,192] -> x2 bf16 NHWC [B,165,32] ----------------
// Stage whole image in LDS as bf16 (rows padded 64->68 shorts), MFMA fragments from LDS,
// stage output tile in LDS, coalesced float4 store. red1 partials as before.
__global__ __launch_bounds__(256) void conv1_mfma(const float* __restrict__ x,
                                                  const float* __restrict__ w1, const float* __restrict__ b1,
                                                  unsigned short* __restrict__ x2, float* __restrict__ red1) {
    constexpr int RS = 68;                              // padded row stride (shorts)
    __shared__ __align__(16) unsigned short xl[3 * 48 * RS];   // 19,584 B
    __shared__ __align__(16) unsigned short ol[165 * 32];      // 10,560 B
    __shared__ float red[176];
    const int img = blockIdx.x;
    const int tid = threadIdx.x;
    const int wave = tid >> 6, lane = tid & 63;
    const int col = lane & 15, quad = lane >> 4;
    if (tid < 176) red[tid] = 0.f;

    // stage image: 9216 floats = 2304 float4, fully coalesced; convert once to bf16
    {
        const float4* xs = (const float4*)(x + (size_t)img * 9216);
        #pragma unroll
        for (int i = 0; i < 9; ++i) {
            const int idx = tid + i * 256;              // float4 index 0..2303
            float4 v = xs[idx];
            const int fo = idx * 4;                     // float offset in image
            const int r = fo >> 6;                      // row = ic*48 + h (64 floats/row)
            const int cf = fo & 63;
            short4_t s;
            s[0] = (short)f2bf(v.x); s[1] = (short)f2bf(v.y);
            s[2] = (short)f2bf(v.z); s[3] = (short)f2bf(v.w);
            *(short4_t*)(xl + r * RS + cf) = s;         // 8B-aligned LDS write
        }
    }

    // weight fragments hoisted: 2 n-tiles x 6 k-chunks (k=(ic,kh,kw) natural order)
    short8 Bf[2][6];
    #pragma unroll
    for (int nt = 0; nt < 2; ++nt) {
        const int oc = nt * 16 + col;
        #pragma unroll
        for (int c = 0; c < 6; ++c)
            Bf[nt][c] = cvt8(w1 + oc * 192 + c * 32 + quad * 8);
    }
    const float bias0 = b1[col], bias1 = b1[col + 16];
    __syncthreads();

    #pragma unroll
    for (int ti = 0; ti < 3; ++ti) {
        const int t = wave + ti * 4;                    // m-tile index, 11 tiles
        if (t >= 11) break;
        const int posA = t * 16 + col;
        const int pm = posA < 165 ? posA : 164;
        const int oh = pm / 15, ow = pm % 15;
        f32x4 acc0 = {0.f, 0.f, 0.f, 0.f}, acc1 = {0.f, 0.f, 0.f, 0.f};
        #pragma unroll
        for (int c = 0; c < 6; ++c) {
            const int ic = c >> 1;
            const int kh = (c & 1) * 4 + quad;
            const unsigned short* ap = xl + (ic * 48 + oh * 4 + kh) * RS + ow * 4;
            short8 af;
            *(short4_t*)&af       = *(const short4_t*)ap;        // 8B-aligned b64 reads
            *((short4_t*)&af + 1) = *(const short4_t*)(ap + 4);
            acc0 = MFMA_BF16(af, Bf[0][c], acc0, 0, 0, 0);
            acc1 = MFMA_BF16(af, Bf[1][c], acc1, 0, 0, 0);
        }
        // C/D: col=lane&15 (oc), row = quad*4+r (pos)
        #pragma unroll
        for (int r = 0; r < 4; ++r) {
            const int pr = t * 16 + quad * 4 + r;
            float v0 = acc0[r] + bias0;
            float v1 = acc1[r] + bias1;
            float s = v0 + v1;
            s += __shfl_xor(s, 1); s += __shfl_xor(s, 2);
            s += __shfl_xor(s, 4); s += __shfl_xor(s, 8);
            if (pr < 165) {
                if (col == 0) atomicAdd(&red[pr], s);
                ol[pr * 32 + col]      = f2bf(frelu(v0));
                ol[pr * 32 + col + 16] = f2bf(frelu(v1));
            }
        }
    }
    __syncthreads();
    // coalesced output store: 10,560 B = 660 float4
    {
        float4* dst = (float4*)(x2 + (size_t)img * 5280);
        const float4* src = (const float4*)ol;
        for (int i = tid; i < 660; i += 256) dst[i] = src[i];
    }
    if (tid < 176) red1[(size_t)tid * 4096 + img] = red[tid];
}

// ---------------- reduce1: ave1[pos] = sum_img red1[pos][img] / 32 ----------------
__global__ __launch_bounds__(256) void reduce1_kernel(const float* __restrict__ red1, float* __restrict__ ave1) {
    const int pos = blockIdx.x;
    float s = 0.f;
    for (int i = threadIdx.x; i < 4096; i += 256) s += red1[(size_t)pos * 4096 + i];
    s += __shfl_down(s, 32); s += __shfl_down(s, 16); s += __shfl_down(s, 8);
    s += __shfl_down(s, 4);  s += __shfl_down(s, 2);  s += __shfl_down(s, 1);
    __shared__ float wsum[4];
    if ((threadIdx.x & 63) == 0) wsum[threadIdx.x >> 6] = s;
    __syncthreads();
    if (threadIdx.x == 0) ave1[pos] = (wsum[0] + wsum[1] + wsum[2] + wsum[3]) * 0.03125f;
}

// ---------------- conv2 (MFMA): x2[B,165,32] * w2p -> x4 bf16 NHWC [B,35,64]; fused ave2 ----------------
// M = 4096*35 = 143360 = 8960 tiles exactly. Block = 16 m-tiles (4 waves x 4).
__global__ __launch_bounds__(256) void conv2_mfma(const unsigned short* __restrict__ x2,
                                                  const unsigned short* __restrict__ w2p, const float* __restrict__ b2,
                                                  unsigned short* __restrict__ x4, float* __restrict__ ave2) {
    __shared__ unsigned short wl[64 * 296];   // rows padded 288->296 (bank spread)
    __shared__ float red[35];
    const int tid = threadIdx.x;
    {
        const float4* src = (const float4*)w2p;   // 2304 float4
        for (int i = tid; i < 2304; i += 256) {
            int row = i / 36, off = i % 36;
            *(float4*)((char*)wl + row * 592 + off * 16) = src[i];
        }
    }
    if (tid < 35) red[tid] = 0.f;
    __syncthreads();

    const int wave = tid >> 6, lane = tid & 63;
    const int col = lane & 15, quad = lane >> 4;
    const int tile0 = blockIdx.x * 16 + wave * 4;

    const unsigned short* abase[4];
    #pragma unroll
    for (int mi = 0; mi < 4; ++mi) {
        const int m = (tile0 + mi) * 16 + col;
        const int b = m / 35, pos = m % 35;
        const int oh = pos / 7, ow = pos % 7;
        abase[mi] = x2 + ((size_t)b * 165 + oh * 30 + ow * 2) * 32 + quad * 8;
    }
    f32x4 acc[4][4] = {};
    #pragma unroll
    for (int c = 0; c < 9; ++c) {             // k' = c*32 + quad*8 + j ; khw = c
        const int kh = c / 3, kw = c % 3;
        short8 Bf[4];
        #pragma unroll
        for (int nt = 0; nt < 4; ++nt)
            Bf[nt] = *(const short8*)((const char*)wl + ((nt * 16 + col) * 296 + c * 32 + quad * 8) * 2);
        #pragma unroll
        for (int mi = 0; mi < 4; ++mi) {
            short8 af = *(const short8*)(abase[mi] + (kh * 15 + kw) * 32);
            #pragma unroll
            for (int nt = 0; nt < 4; ++nt)
                acc[mi][nt] = MFMA_BF16(af, Bf[nt], acc[mi][nt], 0, 0, 0);
        }
    }
    float bv[4];
    #pragma unroll
    for (int nt = 0; nt < 4; ++nt) bv[nt] = b2[nt * 16 + col];
    #pragma unroll
    for (int mi = 0; mi < 4; ++mi) {
        const int mrow0 = (tile0 + mi) * 16;
        #pragma unroll
        for (int r = 0; r < 4; ++r) {
            const int m = mrow0 + quad * 4 + r;
            const int b = m / 35, pos = m % 35;
            unsigned short* dst = x4 + ((size_t)b * 35 + pos) * 64;
            float s = 0.f;
            #pragma unroll
            for (int nt = 0; nt < 4; ++nt) {
                float v = acc[mi][nt][r] + bv[nt];
                s += v;
                dst[nt * 16 + col] = f2bf(frelu(v));
            }
            s += __shfl_xor(s, 1); s += __shfl_xor(s, 2); s += __shfl_xor(s, 4); s += __shfl_xor(s, 8);
            if (col == 0) atomicAdd(&red[pos], s);
        }
    }
    __syncthreads();
    if (tid < 35) atomicAdd(&ave2[tid], red[tid] * 0.015625f);
}

// ---------------- conv3 (MFMA): x4[B,35,64] * w3p -> x6 bf16 [B,960] (NHWC=(pos,oc)); fused ave3 ----------------
// M = 4096*15 = 61440 = 3840 tiles. grid = (240, 2): y splits oc into halves (LDS < 64 KB).
__global__ __launch_bounds__(256) void conv3_mfma(const unsigned short* __restrict__ x4,
                                                  const unsigned short* __restrict__ w3p, const float* __restrict__ b3,
                                                  unsigned short* __restrict__ x6, float* __restrict__ ave3) {
    __shared__ unsigned short wl[32 * 584];   // rows padded 576->584
    __shared__ float red[15];
    const int tid = threadIdx.x;
    const int oc0 = blockIdx.y * 32;
    {
        const float4* src = (const float4*)(w3p + (size_t)oc0 * 576);  // 32*576*2/16 = 2304 float4
        for (int i = tid; i < 2304; i += 256) {
            int row = i / 72, off = i % 72;
            *(float4*)((char*)wl + row * 1168 + off * 16) = src[i];
        }
    }
    if (tid < 15) red[tid] = 0.f;
    __syncthreads();

    const int wave = tid >> 6, lane = tid & 63;
    const int col = lane & 15, quad = lane >> 4;
    const int tile0 = blockIdx.x * 16 + wave * 4;

    const unsigned short* abase[4];
    #pragma unroll
    for (int mi = 0; mi < 4; ++mi) {
        const int m = (tile0 + mi) * 16 + col;
        const int b = m / 15, pos = m % 15;
        const int oh = pos / 5, ow = pos % 5;
        abase[mi] = x4 + ((size_t)b * 35 + oh * 7 + ow) * 64 + quad * 8;
    }
    f32x4 acc[4][2] = {};
    #pragma unroll
    for (int c = 0; c < 18; ++c) {            // k' = c*32 + quad*8 + j ; khw = c>>1, ic = (c&1)*32 + q*8+j
        const int khw = c >> 1, kh = khw / 3, kw = khw % 3;
        const int icoff = (c & 1) * 32;
        short8 Bf[2];
        #pragma unroll
        for (int nt = 0; nt < 2; ++nt)
            Bf[nt] = *(const short8*)((const char*)wl + ((nt * 16 + col) * 584 + c * 32 + quad * 8) * 2);
        #pragma unroll
        for (int mi = 0; mi < 4; ++mi) {
            short8 af = *(const short8*)(abase[mi] + (kh * 7 + kw) * 64 + icoff);
            #pragma unroll
            for (int nt = 0; nt < 2; ++nt)
                acc[mi][nt] = MFMA_BF16(af, Bf[nt], acc[mi][nt], 0, 0, 0);
        }
    }
    float bv[2];
    #pragma unroll
    for (int nt = 0; nt < 2; ++nt) bv[nt] = b3[oc0 + nt * 16 + col];
    #pragma unroll
    for (int mi = 0; mi < 4; ++mi) {
        const int mrow0 = (tile0 + mi) * 16;
        #pragma unroll
        for (int r = 0; r < 4; ++r) {
            const int m = mrow0 + quad * 4 + r;
            const int b = m / 15, pos = m % 15;
            unsigned short* dst = x6 + (size_t)b * 960 + pos * 64 + oc0;
            float s = 0.f;
            #pragma unroll
            for (int nt = 0; nt < 2; ++nt) {
                float v = acc[mi][nt][r] + bv[nt];
                s += v;
                dst[nt * 16 + col] = f2bf(frelu(v));
            }
            s += __shfl_xor(s, 1); s += __shfl_xor(s, 2); s += __shfl_xor(s, 4); s += __shfl_xor(s, 8);
            if (col == 0) atomicAdd(&red[pos], s);
        }
    }
    __syncthreads();
    if (tid < 15) atomicAdd(&ave3[tid], red[tid] * 0.015625f);
}

// ---------------- fc4+fc5 (MFMA): out[b,2] += relu(x6@w4p^T + b4) @ w5^T ----------------
// grid (32,8): 128 m-rows x 64 oc per block; wave: 2 m-tiles x 4 n-tiles, K=30 chunks.
__global__ __launch_bounds__(256) void fc4_mfma(const unsigned short* __restrict__ x6,
                                                const unsigned short* __restrict__ w4p, const float* __restrict__ b4,
                                                const float* __restrict__ w5, float* __restrict__ out) {
    const int tid = threadIdx.x;
    const int wave = tid >> 6, lane = tid & 63;
    const int col = lane & 15, quad = lane >> 4;
    const int m0 = blockIdx.x * 128 + wave * 32;
    const int n0 = blockIdx.y * 64;

    const unsigned short* arow0 = x6 + (size_t)(m0 + col) * 960 + quad * 8;
    const unsigned short* arow1 = arow0 + 16 * 960;
    f32x4 acc[2][4] = {};
    for (int c = 0; c < 30; ++c) {
        short8 Bf[4];
        #pragma unroll
        for (int nt = 0; nt < 4; ++nt)
            Bf[nt] = *(const short8*)(w4p + (size_t)(n0 + nt * 16 + col) * 960 + c * 32 + quad * 8);
        short8 a0 = *(const short8*)(arow0 + c * 32);
        short8 a1 = *(const short8*)(arow1 + c * 32);
        #pragma unroll
        for (int nt = 0; nt < 4; ++nt) {
            acc[0][nt] = MFMA_BF16(a0, Bf[nt], acc[0][nt], 0, 0, 0);
            acc[1][nt] = MFMA_BF16(a1, Bf[nt], acc[1][nt], 0, 0, 0);
        }
    }
    float bv[4], w50[4], w51[4];
    #pragma unroll
    for (int nt = 0; nt < 4; ++nt) {
        const int oc = n0 + nt * 16 + col;
        bv[nt] = b4[oc]; w50[nt] = w5[oc]; w51[nt] = w5[512 + oc];
    }
    #pragma unroll
    for (int mi = 0; mi < 2; ++mi) {
        #pragma unroll
        for (int r = 0; r < 4; ++r) {
            float l0 = 0.f, l1 = 0.f;
            #pragma unroll
            for (int nt = 0; nt < 4; ++nt) {
                float hh = frelu(acc[mi][nt][r] + bv[nt]);
                l0 += hh * w50[nt];
                l1 += hh * w51[nt];
            }
            l0 += __shfl_xor(l0, 1); l0 += __shfl_xor(l0, 2); l0 += __shfl_xor(l0, 4); l0 += __shfl_xor(l0, 8);
            l1 += __shfl_xor(l1, 1); l1 += __shfl_xor(l1, 2); l1 += __shfl_xor(l1, 4); l1 += __shfl_xor(l1, 8);
            if (col == 0) {
                const int gm = m0 + mi * 16 + quad * 4 + r;
                atomicAdd(&out[gm * 2 + 0], l0);
                atomicAdd(&out[gm * 2 + 1], l1);
            }
        }
    }
}

extern "C" void kernel_launch(void* const* d_in, const int* in_sizes, int n_in,
                              void* d_out, int out_size, void* d_ws, size_t ws_size,
                              hipStream_t stream) {
    const float* x  = (const float*)d_in[0];
    const float* w1 = (const float*)d_in[1];
    const float* b1 = (const float*)d_in[2];
    const float* w2 = (const float*)d_in[3];
    const float* b2 = (const float*)d_in[4];
    const float* w3 = (const float*)d_in[5];
    const float* b3 = (const float*)d_in[6];
    const float* w4 = (const float*)d_in[7];
    const float* b4 = (const float*)d_in[8];
    const float* w5 = (const float*)d_in[9];
    const float* b5 = (const float*)d_in[10];
    float* out = (float*)d_out;

    unsigned short* ws = (unsigned short*)d_ws;
    unsigned short* x2  = ws;                      // 21,626,880 ushort
    unsigned short* x4  = ws + 21626880;           //  9,175,040
    unsigned short* x6  = ws + 30801920;           //  3,932,160
    unsigned short* w2p = ws + 34734080;           //     18,432
    unsigned short* w3p = ws + 34752512;           //     36,864
    unsigned short* w4p = ws + 34789376;           //    491,520
    float* red1 = (float*)((char*)d_ws + 70561792); // 176*4096 floats

    float* ave1 = out + 8192;
    float* ave2 = out + 8192 + 165;
    float* ave3 = out + 8192 + 200;

    prep_kernel<<<2169, 256, 0, stream>>>(w2, w3, w4, b5, w2p, w3p, w4p, out);
    conv1_mfma<<<BATCH, 256, 0, stream>>>(x, w1, b1, x2, red1);
    reduce1_kernel<<<165, 256, 0, stream>>>(red1, ave1);
    conv2_mfma<<<560, 256, 0, stream>>>(x2, w2p, b2, x4, ave2);
    conv3_mfma<<<dim3(240, 2), 256, 0, stream>>>(x4, w3p, b3, x6, ave3);
    fc4_mfma<<<dim3(32, 8), 256, 0, stream>>>(x6, w4p, b4, w5, out);
}